// Round 2
// baseline (202.591 us; speedup 1.0000x reference)
//
#include <hip/hip_runtime.h>
#include <hip/hip_bf16.h>
#include <math.h>

#define BATCH 4
#define SEQ   2048
#define DIM   1024
#define HEAD  64

typedef __attribute__((ext_vector_type(8))) short bf16x8;
typedef __attribute__((ext_vector_type(4))) float f32x4;

static __device__ __forceinline__ short f2bf(float f) {
    union { float f; unsigned u; } v;
    v.f = f;
    unsigned r = v.u + 0x7fffu + ((v.u >> 16) & 1u);   // RNE
    return (short)(r >> 16);
}

// ---------------------------------------------------------------------------
// Mask dtype self-detection. JAX bool may arrive as int32 (harness "integer ->
// const int*") or as 1-byte bool. Read first 1024 words as u32: int32 bools
// are only {0,1}; packed bytes show values >1 w.p. 7/8 per word.
// flag=1 -> byte layout, flag=0 -> int32 layout.
// ---------------------------------------------------------------------------
__global__ void detect_mask_kernel(const unsigned int* __restrict__ m,
                                   int* __restrict__ flag) {
    int lane = threadIdx.x & 63;
    bool weird = false;
    for (int i = lane; i < 1024; i += 64) weird |= (m[i] > 1u);
    unsigned long long b = __ballot(weird);
    if (threadIdx.x == 0) *flag = (b != 0ull) ? 1 : 0;
}

// ---------------------------------------------------------------------------
// Projection: X[8192,1024](f32) @ W[1024,64](f32) -> bf16.
// grid (128, 3): y selects (query@Wq->Q, key@Wk->K, value@Wv->Vt).
// Block: 256 threads (4 waves), 64 rows x 64 cols output, K-chunks of 32.
// LDS is frag-major [kgrp][row][8] so ds_read_b128 is lane-contiguous.
// ---------------------------------------------------------------------------
__global__ __launch_bounds__(256) void proj_kernel(
    const float* __restrict__ Xq, const float* __restrict__ Xk, const float* __restrict__ Xv,
    const float* __restrict__ Wq, const float* __restrict__ Wk, const float* __restrict__ Wv,
    short* __restrict__ Q, short* __restrict__ K, short* __restrict__ Vt)
{
    const int which = blockIdx.y;
    const float* __restrict__ X = (which == 0) ? Xq : (which == 1) ? Xk : Xv;
    const float* __restrict__ W = (which == 0) ? Wq : (which == 1) ? Wk : Wv;

    const int row0 = blockIdx.x * 64;
    const int tid  = threadIdx.x;
    const int lane = tid & 63;
    const int wv   = tid >> 6;          // wave 0..3, owns rows wv*16..+15
    const int g    = lane >> 4;         // lane group 0..3
    const int c    = lane & 15;

    __shared__ __align__(16) short A_lds [4][64][8];   // [kgrp][row][8]
    __shared__ __align__(16) short Bt_lds[4][64][8];   // [dgrp][h][8]

    f32x4 acc[4];
    #pragma unroll
    for (int n = 0; n < 4; ++n) acc[n] = (f32x4)0.0f;

    const int arow = tid >> 2, ak8 = tid & 3;   // A staging assignment
    const int bh   = tid & 63, bd  = tid >> 6;  // W staging assignment

    for (int kc = 0; kc < DIM / 32; ++kc) {
        const int kbase = kc * 32;
        // stage A: 8 f32 per thread -> 8 bf16, one b128 LDS store
        {
            const float* src = X + (size_t)(row0 + arow) * DIM + kbase + ak8 * 8;
            f32x4 x0 = *(const f32x4*)(src);
            f32x4 x1 = *(const f32x4*)(src + 4);
            bf16x8 a;
            a[0]=f2bf(x0[0]); a[1]=f2bf(x0[1]); a[2]=f2bf(x0[2]); a[3]=f2bf(x0[3]);
            a[4]=f2bf(x1[0]); a[5]=f2bf(x1[1]); a[6]=f2bf(x1[2]); a[7]=f2bf(x1[3]);
            *(bf16x8*)&A_lds[ak8][arow][0] = a;
        }
        // stage W^T: 8 coalesced strided f32 loads per thread
        {
            bf16x8 bbv;
            #pragma unroll
            for (int j = 0; j < 8; ++j)
                bbv[j] = f2bf(W[(size_t)(kbase + bd * 8 + j) * HEAD + bh]);
            *(bf16x8*)&Bt_lds[bd][bh][0] = bbv;
        }
        __syncthreads();

        bf16x8 av = *(bf16x8*)&A_lds[g][wv * 16 + c][0];
        #pragma unroll
        for (int n = 0; n < 4; ++n) {
            bf16x8 bv = *(bf16x8*)&Bt_lds[g][n * 16 + c][0];
            acc[n] = __builtin_amdgcn_mfma_f32_16x16x32_bf16(av, bv, acc[n], 0, 0, 0);
        }
        __syncthreads();
    }

    // D layout: col = lane&15, row = (lane>>4)*4 + reg   [measured m89]
    if (which < 2) {
        short* dst = (which == 0) ? Q : K;
        #pragma unroll
        for (int n = 0; n < 4; ++n)
            #pragma unroll
            for (int r = 0; r < 4; ++r) {
                int row = row0 + wv * 16 + g * 4 + r;
                dst[(size_t)row * HEAD + n * 16 + c] = f2bf(acc[n][r]);
            }
    } else {
        #pragma unroll
        for (int n = 0; n < 4; ++n)
            #pragma unroll
            for (int r = 0; r < 4; ++r) {
                int row = row0 + wv * 16 + g * 4 + r;   // global b*S+s
                int b = row >> 11, s = row & (SEQ - 1);
                int h = n * 16 + c;
                Vt[((size_t)b * HEAD + h) * SEQ + s] = f2bf(acc[n][r]);
            }
    }
}

// ---------------------------------------------------------------------------
// Flash attention: grid (S/32, B), 128 threads (2 waves x 16 q-rows).
// Online softmax over key tiles of 32. mask==true -> -inf before softmax.
// Mask layout (byte vs int32) selected by runtime flag from detect kernel.
// ---------------------------------------------------------------------------
__global__ __launch_bounds__(128) void attn_kernel(
    const short* __restrict__ Q, const short* __restrict__ K, const short* __restrict__ Vt,
    const void* __restrict__ mask, const int* __restrict__ mflag,
    float* __restrict__ out)
{
    const int qb = blockIdx.x;
    const int b  = blockIdx.y;
    const int qbase = qb * 32;
    const int tid  = threadIdx.x;
    const int lane = tid & 63;
    const int wv   = tid >> 6;          // 0..1
    const int g    = lane >> 4;
    const int c    = lane & 15;

    const short* Qb = Q  + (size_t)(b * SEQ + qbase) * HEAD;
    const short* Kb = K  + (size_t)b * SEQ * HEAD;
    const short* Vb = Vt + (size_t)b * HEAD * SEQ;
    const size_t mbase = (size_t)b * SEQ * SEQ + (size_t)qbase * SEQ;
    const unsigned char* Mb8 = (const unsigned char*)mask + mbase;
    const int*           Mb32 = (const int*)mask + mbase;
    const int useByte = *mflag;   // grid-uniform

    __shared__ __align__(16) short K_lds[8][32][8];     // [hgrp][krow][8]
    __shared__ __align__(16) short V_lds[4][64][8];     // [kgrp][h][8]
    __shared__ __align__(16) short P_lds[2][4][16][8];  // [wave][kgrp][qrow][8]

    // Q fragments in registers (A operand, rows wv*16..+15)
    bf16x8 qa0 = *(const bf16x8*)&Qb[(wv * 16 + c) * HEAD + g * 8];
    bf16x8 qa1 = *(const bf16x8*)&Qb[(wv * 16 + c) * HEAD + 32 + g * 8];

    float m[4], l[4];
    f32x4 o[4];
    #pragma unroll
    for (int r = 0; r < 4; ++r) { m[r] = -INFINITY; l[r] = 0.0f; }
    #pragma unroll
    for (int n = 0; n < 4; ++n) o[n] = (f32x4)0.0f;

    const float scale = 0.125f;                    // HEAD^-0.5
    const float LOG2E = 1.44269504088896340736f;

    for (int kt = 0; kt < SEQ / 32; ++kt) {
        // stage K tile (32x64) and V^T tile (64x32), frag-major
        #pragma unroll
        for (int i = 0; i < 2; ++i) {
            int idx = tid + i * 128;
            int krow = idx >> 3, hg = idx & 7;
            *(bf16x8*)&K_lds[hg][krow][0] =
                *(const bf16x8*)&Kb[(size_t)(kt * 32 + krow) * HEAD + hg * 8];
        }
        #pragma unroll
        for (int i = 0; i < 2; ++i) {
            int idx = tid + i * 128;
            int h = idx >> 2, kg = idx & 3;
            *(bf16x8*)&V_lds[kg][h][0] =
                *(const bf16x8*)&Vb[(size_t)h * SEQ + kt * 32 + kg * 8];
        }
        __syncthreads();

        // QK^T: 16 q x 32 k, reduce over h=64 (2 chained MFMAs per 16-k frag)
        f32x4 s0 = (f32x4)0.0f, s1 = (f32x4)0.0f;
        {
            bf16x8 kb;
            kb = *(bf16x8*)&K_lds[g][c][0];
            s0 = __builtin_amdgcn_mfma_f32_16x16x32_bf16(qa0, kb, s0, 0, 0, 0);
            kb = *(bf16x8*)&K_lds[4 + g][c][0];
            s0 = __builtin_amdgcn_mfma_f32_16x16x32_bf16(qa1, kb, s0, 0, 0, 0);
            kb = *(bf16x8*)&K_lds[g][16 + c][0];
            s1 = __builtin_amdgcn_mfma_f32_16x16x32_bf16(qa0, kb, s1, 0, 0, 0);
            kb = *(bf16x8*)&K_lds[4 + g][16 + c][0];
            s1 = __builtin_amdgcn_mfma_f32_16x16x32_bf16(qa1, kb, s1, 0, 0, 0);
        }

        // scale + mask (mask true -> -inf)
        float sv0[4], sv1[4];
        #pragma unroll
        for (int r = 0; r < 4; ++r) {
            size_t off = (size_t)(wv * 16 + g * 4 + r) * SEQ + kt * 32 + c;
            bool mk0, mk1;
            if (useByte) { mk0 = Mb8[off]  != 0; mk1 = Mb8[off + 16]  != 0; }
            else         { mk0 = Mb32[off] != 0; mk1 = Mb32[off + 16] != 0; }
            sv0[r] = mk0 ? -INFINITY : s0[r] * scale;
            sv1[r] = mk1 ? -INFINITY : s1[r] * scale;
        }

        // online softmax (rows live in 16-lane groups; shfl stays in-group)
        float pr0[4], pr1[4], cf[4];
        #pragma unroll
        for (int r = 0; r < 4; ++r) {
            float mx = fmaxf(sv0[r], sv1[r]);
            #pragma unroll
            for (int d = 1; d < 16; d <<= 1) mx = fmaxf(mx, __shfl_xor(mx, d));
            float mn = fmaxf(m[r], mx);
            cf[r] = (m[r] == mn) ? 1.0f : exp2f((m[r] - mn) * LOG2E);
            pr0[r] = (sv0[r] <= -1e37f) ? 0.0f : exp2f((sv0[r] - mn) * LOG2E);
            pr1[r] = (sv1[r] <= -1e37f) ? 0.0f : exp2f((sv1[r] - mn) * LOG2E);
            float rs = pr0[r] + pr1[r];
            #pragma unroll
            for (int d = 1; d < 16; d <<= 1) rs += __shfl_xor(rs, d);
            l[r] = l[r] * cf[r] + rs;
            m[r] = mn;
        }
        #pragma unroll
        for (int n = 0; n < 4; ++n)
            #pragma unroll
            for (int r = 0; r < 4; ++r) o[n][r] *= cf[r];

        // P -> wave-private LDS (transpose into A-fragment layout)
        #pragma unroll
        for (int r = 0; r < 4; ++r) {
            P_lds[wv][(c >> 3)][g * 4 + r][c & 7]     = f2bf(pr0[r]);
            P_lds[wv][2 + (c >> 3)][g * 4 + r][c & 7] = f2bf(pr1[r]);
        }
        // same-wave LDS write->read: in-wave DS ordering + compiler lgkmcnt
        bf16x8 pa = *(bf16x8*)&P_lds[wv][g][c][0];
        #pragma unroll
        for (int n = 0; n < 4; ++n) {
            bf16x8 vbv = *(bf16x8*)&V_lds[g][n * 16 + c][0];
            o[n] = __builtin_amdgcn_mfma_f32_16x16x32_bf16(pa, vbv, o[n], 0, 0, 0);
        }
        __syncthreads();
    }

    // epilogue: normalize and store f32
    float* Ob = out + (size_t)(b * SEQ + qbase) * HEAD;
    #pragma unroll
    for (int r = 0; r < 4; ++r) {
        float inv = 1.0f / l[r];
        #pragma unroll
        for (int n = 0; n < 4; ++n)
            Ob[(size_t)(wv * 16 + g * 4 + r) * HEAD + n * 16 + c] = o[n][r] * inv;
    }
}

extern "C" void kernel_launch(void* const* d_in, const int* in_sizes, int n_in,
                              void* d_out, int out_size, void* d_ws, size_t ws_size,
                              hipStream_t stream)
{
    // setup_inputs order: key_input, query_input, value_input, mask, Wq, Wk, Wv
    const float* key_in   = (const float*)d_in[0];
    const float* query_in = (const float*)d_in[1];
    const float* value_in = (const float*)d_in[2];
    const void*  mask     = d_in[3];
    const float* Wq = (const float*)d_in[4];
    const float* Wk = (const float*)d_in[5];
    const float* Wv = (const float*)d_in[6];

    short* Qw  = (short*)d_ws;                          // [B*S, 64] bf16 (1 MB)
    short* Kw  = Qw + (size_t)BATCH * SEQ * HEAD;       // [B*S, 64] bf16 (1 MB)
    short* Vtw = Kw + (size_t)BATCH * SEQ * HEAD;       // [B, 64, S] bf16 (1 MB)
    int* mflag = (int*)((char*)d_ws + (size_t)3 * BATCH * SEQ * HEAD * sizeof(short));

    detect_mask_kernel<<<1, 64, 0, stream>>>((const unsigned int*)mask, mflag);

    proj_kernel<<<dim3(BATCH * SEQ / 64, 3), 256, 0, stream>>>(
        query_in, key_in, value_in, Wq, Wk, Wv, Qw, Kw, Vtw);

    attn_kernel<<<dim3(SEQ / 32, BATCH), 128, 0, stream>>>(
        Qw, Kw, Vtw, mask, mflag, (float*)d_out);
}

// Round 3
// 75.957 us; speedup vs baseline: 2.6672x; 2.6672x over previous
//
#include <hip/hip_runtime.h>
#include <hip/hip_bf16.h>
#include <math.h>

#define BATCH 4
#define SEQ   2048
#define DIM   1024
#define HEAD  64

typedef __attribute__((ext_vector_type(8))) short bf16x8;
typedef __attribute__((ext_vector_type(4))) float f32x4;

static __device__ __forceinline__ short f2bf(float f) {
    union { float f; unsigned u; } v;
    v.f = f;
    unsigned r = v.u + 0x7fffu + ((v.u >> 16) & 1u);   // RNE
    return (short)(r >> 16);
}

// ---------------------------------------------------------------------------
// Mask dtype self-detection (bool-as-byte vs int32). int32 bools are {0,1};
// packed bytes read as u32 exceed 1 w.p. 7/8 per word.
// ---------------------------------------------------------------------------
__global__ void detect_mask_kernel(const unsigned int* __restrict__ m,
                                   int* __restrict__ flag) {
    int lane = threadIdx.x & 63;
    bool weird = false;
    for (int i = lane; i < 1024; i += 64) weird |= (m[i] > 1u);
    unsigned long long b = __ballot(weird);
    if (threadIdx.x == 0) *flag = (b != 0ull) ? 1 : 0;
}

// ---------------------------------------------------------------------------
// Projection: X[8192,1024](f32) @ W[1024,64](f32) -> bf16. (unchanged)
// ---------------------------------------------------------------------------
__global__ __launch_bounds__(256) void proj_kernel(
    const float* __restrict__ Xq, const float* __restrict__ Xk, const float* __restrict__ Xv,
    const float* __restrict__ Wq, const float* __restrict__ Wk, const float* __restrict__ Wv,
    short* __restrict__ Q, short* __restrict__ K, short* __restrict__ Vt)
{
    const int which = blockIdx.y;
    const float* __restrict__ X = (which == 0) ? Xq : (which == 1) ? Xk : Xv;
    const float* __restrict__ W = (which == 0) ? Wq : (which == 1) ? Wk : Wv;

    const int row0 = blockIdx.x * 64;
    const int tid  = threadIdx.x;
    const int lane = tid & 63;
    const int wv   = tid >> 6;
    const int g    = lane >> 4;
    const int c    = lane & 15;

    __shared__ __align__(16) short A_lds [4][64][8];   // [kgrp][row][8]
    __shared__ __align__(16) short Bt_lds[4][64][8];   // [dgrp][h][8]

    f32x4 acc[4];
    #pragma unroll
    for (int n = 0; n < 4; ++n) acc[n] = (f32x4)0.0f;

    const int arow = tid >> 2, ak8 = tid & 3;
    const int bh   = tid & 63, bd  = tid >> 6;

    for (int kc = 0; kc < DIM / 32; ++kc) {
        const int kbase = kc * 32;
        {
            const float* src = X + (size_t)(row0 + arow) * DIM + kbase + ak8 * 8;
            f32x4 x0 = *(const f32x4*)(src);
            f32x4 x1 = *(const f32x4*)(src + 4);
            bf16x8 a;
            a[0]=f2bf(x0[0]); a[1]=f2bf(x0[1]); a[2]=f2bf(x0[2]); a[3]=f2bf(x0[3]);
            a[4]=f2bf(x1[0]); a[5]=f2bf(x1[1]); a[6]=f2bf(x1[2]); a[7]=f2bf(x1[3]);
            *(bf16x8*)&A_lds[ak8][arow][0] = a;
        }
        {
            bf16x8 bbv;
            #pragma unroll
            for (int j = 0; j < 8; ++j)
                bbv[j] = f2bf(W[(size_t)(kbase + bd * 8 + j) * HEAD + bh]);
            *(bf16x8*)&Bt_lds[bd][bh][0] = bbv;
        }
        __syncthreads();

        bf16x8 av = *(bf16x8*)&A_lds[g][wv * 16 + c][0];
        #pragma unroll
        for (int n = 0; n < 4; ++n) {
            bf16x8 bv = *(bf16x8*)&Bt_lds[g][n * 16 + c][0];
            acc[n] = __builtin_amdgcn_mfma_f32_16x16x32_bf16(av, bv, acc[n], 0, 0, 0);
        }
        __syncthreads();
    }

    if (which < 2) {
        short* dst = (which == 0) ? Q : K;
        #pragma unroll
        for (int n = 0; n < 4; ++n)
            #pragma unroll
            for (int r = 0; r < 4; ++r) {
                int row = row0 + wv * 16 + g * 4 + r;
                dst[(size_t)row * HEAD + n * 16 + c] = f2bf(acc[n][r]);
            }
    } else {
        #pragma unroll
        for (int n = 0; n < 4; ++n)
            #pragma unroll
            for (int r = 0; r < 4; ++r) {
                int row = row0 + wv * 16 + g * 4 + r;
                int b = row >> 11, s = row & (SEQ - 1);
                int h = n * 16 + c;
                Vt[((size_t)b * HEAD + h) * SEQ + s] = f2bf(acc[n][r]);
            }
    }
}

// ---------------------------------------------------------------------------
// Flash attention v2: grid (S/16, B), 512 threads = 8 waves.
// Block owns 16 q-rows; wave w owns keys [w*256, (w+1)*256) with private
// online softmax; segments merged via LDS at the end (single barrier).
// K/V are L2-resident (256 KB/batch) -> loaded straight to registers, no
// staging. Mask layout (byte vs int32) via runtime flag.
// ---------------------------------------------------------------------------
__global__ __launch_bounds__(512, 4) void attn_kernel(
    const short* __restrict__ Q, const short* __restrict__ K, const short* __restrict__ Vt,
    const void* __restrict__ mask, const int* __restrict__ mflag,
    float* __restrict__ out)
{
    const int qbase = blockIdx.x * 16;
    const int b     = blockIdx.y;
    const int tid  = threadIdx.x;
    const int lane = tid & 63;
    const int w    = tid >> 6;          // wave 0..7 = key segment
    const int g    = lane >> 4;
    const int c    = lane & 15;

    const short* Qb = Q  + (size_t)(b * SEQ + qbase) * HEAD;
    const short* Kb = K  + (size_t)b * SEQ * HEAD;
    const short* Vb = Vt + (size_t)b * HEAD * SEQ;
    const size_t mbase = (size_t)b * SEQ * SEQ + (size_t)qbase * SEQ;
    const unsigned char* Mb8  = (const unsigned char*)mask + mbase;
    const int*           Mb32 = (const int*)mask + mbase;
    const int useByte = *mflag;

    __shared__ __align__(16) short P_lds[8][4][16][8];  // [wave][kgrp][qrow][8]
    __shared__ float O_lds[8][16][64];                  // per-wave partial O
    __shared__ float M_lds[8][16];                      // per-wave row max
    __shared__ float L_lds[8][16];                      // per-wave row sum

    // Q A-fragments (rows qbase..qbase+15), shared by all waves via L2
    bf16x8 qa0 = *(const bf16x8*)&Qb[c * HEAD + g * 8];
    bf16x8 qa1 = *(const bf16x8*)&Qb[c * HEAD + 32 + g * 8];

    float m[4], l[4];
    f32x4 o[4];
    #pragma unroll
    for (int r = 0; r < 4; ++r) { m[r] = -INFINITY; l[r] = 0.0f; }
    #pragma unroll
    for (int n = 0; n < 4; ++n) o[n] = (f32x4)0.0f;

    const float scale = 0.125f;                    // HEAD^-0.5
    const float LOG2E = 1.44269504088896340736f;

    for (int i = 0; i < 8; ++i) {
        const int kt = w * 8 + i;                  // key tile of 32
        const short* Kt = Kb + (size_t)kt * 32 * HEAD;

        // K B-fragments straight from global (L2-hit)
        bf16x8 kb00 = *(const bf16x8*)&Kt[c * HEAD + g * 8];
        bf16x8 kb01 = *(const bf16x8*)&Kt[c * HEAD + 32 + g * 8];
        bf16x8 kb10 = *(const bf16x8*)&Kt[(16 + c) * HEAD + g * 8];
        bf16x8 kb11 = *(const bf16x8*)&Kt[(16 + c) * HEAD + 32 + g * 8];

        // V^T B-fragments for the PV step
        bf16x8 vb[4];
        #pragma unroll
        for (int n = 0; n < 4; ++n)
            vb[n] = *(const bf16x8*)&Vb[(size_t)(n * 16 + c) * SEQ + kt * 32 + g * 8];

        f32x4 s0 = (f32x4)0.0f, s1 = (f32x4)0.0f;
        s0 = __builtin_amdgcn_mfma_f32_16x16x32_bf16(qa0, kb00, s0, 0, 0, 0);
        s0 = __builtin_amdgcn_mfma_f32_16x16x32_bf16(qa1, kb01, s0, 0, 0, 0);
        s1 = __builtin_amdgcn_mfma_f32_16x16x32_bf16(qa0, kb10, s1, 0, 0, 0);
        s1 = __builtin_amdgcn_mfma_f32_16x16x32_bf16(qa1, kb11, s1, 0, 0, 0);

        // scale + mask (mask true -> -inf)
        float sv0[4], sv1[4];
        #pragma unroll
        for (int r = 0; r < 4; ++r) {
            size_t off = (size_t)(g * 4 + r) * SEQ + kt * 32 + c;
            bool mk0, mk1;
            if (useByte) { mk0 = Mb8[off]  != 0; mk1 = Mb8[off + 16]  != 0; }
            else         { mk0 = Mb32[off] != 0; mk1 = Mb32[off + 16] != 0; }
            sv0[r] = mk0 ? -INFINITY : s0[r] * scale;
            sv1[r] = mk1 ? -INFINITY : s1[r] * scale;
        }

        // online softmax (rows live in 16-lane groups)
        float pr0[4], pr1[4], cf[4];
        #pragma unroll
        for (int r = 0; r < 4; ++r) {
            float mx = fmaxf(sv0[r], sv1[r]);
            #pragma unroll
            for (int d = 1; d < 16; d <<= 1) mx = fmaxf(mx, __shfl_xor(mx, d));
            float mn = fmaxf(m[r], mx);
            cf[r] = (m[r] == mn) ? 1.0f : exp2f((m[r] - mn) * LOG2E);
            pr0[r] = (sv0[r] <= -1e37f) ? 0.0f : exp2f((sv0[r] - mn) * LOG2E);
            pr1[r] = (sv1[r] <= -1e37f) ? 0.0f : exp2f((sv1[r] - mn) * LOG2E);
            float rs = pr0[r] + pr1[r];
            #pragma unroll
            for (int d = 1; d < 16; d <<= 1) rs += __shfl_xor(rs, d);
            l[r] = l[r] * cf[r] + rs;
            m[r] = mn;
        }
        #pragma unroll
        for (int n = 0; n < 4; ++n)
            #pragma unroll
            for (int r = 0; r < 4; ++r) o[n][r] *= cf[r];

        // P transpose through wave-private LDS into A-fragment layout
        #pragma unroll
        for (int r = 0; r < 4; ++r) {
            P_lds[w][(c >> 3)][g * 4 + r][c & 7]     = f2bf(pr0[r]);
            P_lds[w][2 + (c >> 3)][g * 4 + r][c & 7] = f2bf(pr1[r]);
        }
        bf16x8 pa = *(bf16x8*)&P_lds[w][g][c][0];
        #pragma unroll
        for (int n = 0; n < 4; ++n)
            o[n] = __builtin_amdgcn_mfma_f32_16x16x32_bf16(pa, vb[n], o[n], 0, 0, 0);
    }

    // publish per-wave partials
    #pragma unroll
    for (int n = 0; n < 4; ++n)
        #pragma unroll
        for (int r = 0; r < 4; ++r)
            O_lds[w][g * 4 + r][n * 16 + c] = o[n][r];
    if (c == 0) {
        #pragma unroll
        for (int r = 0; r < 4; ++r) {
            M_lds[w][g * 4 + r] = m[r];
            L_lds[w][g * 4 + r] = l[r];
        }
    }
    __syncthreads();

    // merge 8 segments: 512 threads cover 16x64 outputs, 2 cols each
    const int row  = tid >> 5;
    const int col0 = (tid & 31) * 2;
    float M = -INFINITY;
    #pragma unroll
    for (int i = 0; i < 8; ++i) M = fmaxf(M, M_lds[i][row]);
    float L = 0.0f, a0 = 0.0f, a1 = 0.0f;
    #pragma unroll
    for (int i = 0; i < 8; ++i) {
        float wgt = exp2f((M_lds[i][row] - M) * LOG2E);
        L  += L_lds[i][row] * wgt;
        a0 += O_lds[i][row][col0]     * wgt;
        a1 += O_lds[i][row][col0 + 1] * wgt;
    }
    float inv = 1.0f / L;
    float* Ob = out + (size_t)(b * SEQ + qbase + row) * HEAD;
    Ob[col0]     = a0 * inv;
    Ob[col0 + 1] = a1 * inv;
}

extern "C" void kernel_launch(void* const* d_in, const int* in_sizes, int n_in,
                              void* d_out, int out_size, void* d_ws, size_t ws_size,
                              hipStream_t stream)
{
    // setup_inputs order: key_input, query_input, value_input, mask, Wq, Wk, Wv
    const float* key_in   = (const float*)d_in[0];
    const float* query_in = (const float*)d_in[1];
    const float* value_in = (const float*)d_in[2];
    const void*  mask     = d_in[3];
    const float* Wq = (const float*)d_in[4];
    const float* Wk = (const float*)d_in[5];
    const float* Wv = (const float*)d_in[6];

    short* Qw  = (short*)d_ws;                          // [B*S, 64] bf16 (1 MB)
    short* Kw  = Qw + (size_t)BATCH * SEQ * HEAD;       // [B*S, 64] bf16 (1 MB)
    short* Vtw = Kw + (size_t)BATCH * SEQ * HEAD;       // [B, 64, S] bf16 (1 MB)
    int* mflag = (int*)((char*)d_ws + (size_t)3 * BATCH * SEQ * HEAD * sizeof(short));

    detect_mask_kernel<<<1, 64, 0, stream>>>((const unsigned int*)mask, mflag);

    proj_kernel<<<dim3(BATCH * SEQ / 64, 3), 256, 0, stream>>>(
        query_in, key_in, value_in, Wq, Wk, Wv, Qw, Kw, Vtw);

    attn_kernel<<<dim3(SEQ / 16, BATCH), 512, 0, stream>>>(
        Qw, Kw, Vtw, mask, mflag, (float*)d_out);
}